// Round 10
// baseline (997.593 us; speedup 1.0000x reference)
//
#include <hip/hip_runtime.h>

#define TPB 256

typedef unsigned int uint32;
typedef float float4v __attribute__((ext_vector_type(4)));
typedef unsigned int uint4v __attribute__((ext_vector_type(4)));

static __device__ __forceinline__ unsigned short f2bf(float f) {
  unsigned int u = __float_as_uint(f);
  unsigned int r = (u + 0x7FFFu + ((u >> 16) & 1u)) >> 16;
  return (unsigned short)r;
}
static __device__ __forceinline__ float bf_lo(uint32 v) {
  return __uint_as_float(v << 16);
}
static __device__ __forceinline__ float bf_hi(uint32 v) {
  return __uint_as_float(v & 0xFFFF0000u);
}

// int64 staged => odd int32 words (high words) of src row are 0.
static __device__ __forceinline__ int edge_val(const int* __restrict__ ep,
                                               long long idx, int is64) {
  return is64 ? ep[2 * idx] : ep[idx];
}

__global__ void k_detect(const int* __restrict__ ep, long long E,
                         int* __restrict__ flag) {
  int lim = (E < 16384) ? (int)E : 16384;
  int found = 0;
  for (int i = threadIdx.x; i < lim; i += TPB) found |= (ep[2 * i + 1] != 0);
  if (found) atomicOr(flag, 1);
}

__global__ void k_count(const int* __restrict__ ep, long long E,
                        const int* __restrict__ flag, int* __restrict__ deg) {
  int is64 = (*flag == 0);
  long long stride = (long long)gridDim.x * blockDim.x;
  for (long long e = blockIdx.x * (long long)blockDim.x + threadIdx.x; e < E;
       e += stride) {
    int d = edge_val(ep, E + e, is64);
    atomicAdd(&deg[d], 1);
  }
}

__global__ void k_bsum(const int* __restrict__ deg, int N,
                       int* __restrict__ bsums) {
  __shared__ int lds[TPB];
  int t = threadIdx.x;
  int i = blockIdx.x * TPB + t;
  lds[t] = (i < N) ? deg[i] : 0;
  __syncthreads();
  for (int off = TPB / 2; off > 0; off >>= 1) {
    if (t < off) lds[t] += lds[t + off];
    __syncthreads();
  }
  if (t == 0) bsums[blockIdx.x] = lds[0];
}

__global__ void k_bscan(int* __restrict__ bsums, int nb) {
  __shared__ int lds[512];
  int t = threadIdx.x;
  int v = (t < nb) ? bsums[t] : 0;
  lds[t] = v;
  __syncthreads();
  for (int off = 1; off < 512; off <<= 1) {
    int x = (t >= off) ? lds[t - off] : 0;
    __syncthreads();
    lds[t] += x;
    __syncthreads();
  }
  if (t < nb) bsums[t] = lds[t] - v;  // exclusive
}

__global__ void k_scan3(const int* __restrict__ deg, const int* __restrict__ bsums,
                        int N, int* __restrict__ row_start, int* __restrict__ cursor,
                        float* __restrict__ r) {
  __shared__ int lds[TPB];
  int t = threadIdx.x;
  int i = blockIdx.x * TPB + t;
  int v = (i < N) ? deg[i] : 0;
  lds[t] = v;
  __syncthreads();
  for (int off = 1; off < TPB; off <<= 1) {
    int x = (t >= off) ? lds[t - off] : 0;
    __syncthreads();
    lds[t] += x;
    __syncthreads();
  }
  if (i < N) {
    int ex = lds[t] - v + bsums[blockIdx.x];
    row_start[i] = ex;
    cursor[i] = ex;
    r[i] = rsqrtf((float)(v + 1));
  }
}

__global__ void k_fill(const int* __restrict__ ep, long long E,
                       const int* __restrict__ flag, int* __restrict__ cursor,
                       int* __restrict__ csr_src) {
  int is64 = (*flag == 0);
  long long stride = (long long)gridDim.x * blockDim.x;
  for (long long e = blockIdx.x * (long long)blockDim.x + threadIdx.x; e < E;
       e += stride) {
    int s = edge_val(ep, e, is64);
    int d = edge_val(ep, E + e, is64);
    int pos = atomicAdd(&cursor[d], 1);
    __builtin_nontemporal_store(s, &csr_src[pos]);
  }
}

// out[row,:] = bf16( (X@W) * r[row] ).  W packed bf16-pairs in LDS (32 KB).
__global__ __launch_bounds__(TPB, 4) void k_gemm(
    const float* __restrict__ X, const float* __restrict__ W,
    const float* __restrict__ r, unsigned short* __restrict__ outB, int N) {
  __shared__ uint32 wl[128 * 64];  // [k][pair]
  for (int i = threadIdx.x; i < 128 * 64; i += TPB) {
    int k = i >> 6, p = i & 63;
    float2 wv = *reinterpret_cast<const float2*>(&W[k * 128 + p * 2]);
    wl[i] = (uint32)f2bf(wv.x) | ((uint32)f2bf(wv.y) << 16);
  }
  __syncthreads();
  int wave = threadIdx.x >> 6, lane = threadIdx.x & 63;
  int row0 = (blockIdx.x * 4 + wave) * 8;
  if (row0 >= N) return;
  const int c0 = lane * 2;
  float2 acc[8];
#pragma unroll
  for (int q = 0; q < 8; q++) acc[q] = make_float2(0.f, 0.f);
  for (int kk = 0; kk < 128; kk += 4) {
    float4v xv[8];
#pragma unroll
    for (int q = 0; q < 8; q++) {
      int rr = row0 + q;
      if (rr >= N) rr = N - 1;
      xv[q] = __builtin_nontemporal_load(
          reinterpret_cast<const float4v*>(&X[(size_t)rr * 128 + kk]));
    }
#pragma unroll
    for (int u = 0; u < 4; u++) {
      uint32 wv = wl[(kk + u) * 64 + lane];
      float wx = bf_lo(wv), wy = bf_hi(wv);
#pragma unroll
      for (int q = 0; q < 8; q++) {
        float xk = xv[q][u];
        acc[q].x = fmaf(xk, wx, acc[q].x);
        acc[q].y = fmaf(xk, wy, acc[q].y);
      }
    }
  }
#pragma unroll
  for (int q = 0; q < 8; q++) {
    int rr = row0 + q;
    if (rr < N) {
      float sc = r[rr];
      uint32 o = (uint32)f2bf(acc[q].x * sc) | ((uint32)f2bf(acc[q].y * sc) << 16);
      *reinterpret_cast<uint32*>(&outB[(size_t)rr * 128 + c0]) = o;
    }
  }
}

// mini-gemm epilogue for the fused layer-1 kernel:
// Y row (this wave) -> Hs2[i,:] = bf16( (Y @ W2) * r[i] ), lane owns 2 cols.
static __device__ __forceinline__ void y_to_hs2(
    float v0, float v1, float ri, int i, int wave, int lane, int c0,
    const uint32* __restrict__ w2l, float* __restrict__ yrow,
    unsigned short* __restrict__ outB) {
  float* yw = yrow + wave * 128;
  *reinterpret_cast<float2*>(&yw[lane * 2]) = make_float2(v0, v1);
  float hx = 0.f, hy = 0.f;
  for (int k4 = 0; k4 < 32; k4++) {
    float4v y4 = *reinterpret_cast<const float4v*>(&yw[k4 * 4]);  // broadcast
#pragma unroll
    for (int j = 0; j < 4; j++) {
      uint32 wv = w2l[(k4 * 4 + j) * 64 + lane];
      hx = fmaf(y4[j], bf_lo(wv), hx);
      hy = fmaf(y4[j], bf_hi(wv), hy);
    }
  }
  uint32 o = (uint32)f2bf(hx * ri) | ((uint32)f2bf(hy * ri) << 16);
  *reinterpret_cast<uint32*>(&outB[(size_t)i * 128 + c0]) = o;  // normal store: keep L3-resident
}

// ---------------------------------------------------------------------------
// FUSED layer-1 aggregation + layer-2 gemm:
//   Y_i = relu( r_i*(Hs1_i + sum_src Hs1_src) + b1 )   (in registers/LDS only)
//   Hs2_i = bf16( (Y_i @ W2) * r_i )                    (written to outB)
// Gather structure identical to round-8 (measured 151us).
// ---------------------------------------------------------------------------
__global__ __launch_bounds__(TPB) void k_aggF(
    const unsigned short* __restrict__ HsB, const float* __restrict__ r,
    const int* __restrict__ row_start, const int* __restrict__ deg,
    const int* __restrict__ csr_src, const float* __restrict__ bias,
    const float* __restrict__ W2, unsigned short* __restrict__ outB, int N) {
  __shared__ uint32 w2l[128 * 64];  // 32 KB bf16-packed W2 [k][pair]
  __shared__ float yrow[4 * 128];   // 2 KB per-wave Y row
  for (int i = threadIdx.x; i < 128 * 64; i += TPB) {
    int k = i >> 6, p = i & 63;
    float2 wv = *reinterpret_cast<const float2*>(&W2[k * 128 + p * 2]);
    w2l[i] = (uint32)f2bf(wv.x) | ((uint32)f2bf(wv.y) << 16);
  }
  __syncthreads();
  int wave = threadIdx.x >> 6, lane = threadIdx.x & 63;
  int gw = blockIdx.x * 4 + wave, nw = gridDim.x * 4;
  const int c0 = lane * 2;
  float2 b = *reinterpret_cast<const float2*>(&bias[c0]);

  for (int i0 = gw; i0 < N; i0 += 2 * nw) {
    const int iA = i0;
    const int iB = i0 + nw;
    const int hasB = (iB < N);
    int sA = __builtin_amdgcn_readfirstlane(row_start[iA]);
    int dA = __builtin_amdgcn_readfirstlane(deg[iA]);
    int sB = 0, dB = 0;
    if (hasB) {
      sB = __builtin_amdgcn_readfirstlane(row_start[iB]);
      dB = __builtin_amdgcn_readfirstlane(deg[iB]);
    }
    uint32 selfA = *reinterpret_cast<const uint32*>(&HsB[(size_t)iA * 128 + c0]);
    float2 aA = make_float2(bf_lo(selfA), bf_hi(selfA));
    float2 aB = make_float2(0.f, 0.f);
    if (hasB) {
      uint32 selfB = *reinterpret_cast<const uint32*>(&HsB[(size_t)iB * 128 + c0]);
      aB = make_float2(bf_lo(selfB), bf_hi(selfB));
    }
    int jA = 0, jB = 0;
    while (jA + 8 <= dA && jB + 8 <= dB) {
      int ia[8], ib[8];
#pragma unroll
      for (int u = 0; u < 8; u++) ia[u] = csr_src[sA + jA + u];
#pragma unroll
      for (int u = 0; u < 8; u++) ib[u] = csr_src[sB + jB + u];
      uint32 va[8], vb[8];
#pragma unroll
      for (int u = 0; u < 8; u++)
        va[u] = *reinterpret_cast<const uint32*>(&HsB[(size_t)ia[u] * 128 + c0]);
#pragma unroll
      for (int u = 0; u < 8; u++)
        vb[u] = *reinterpret_cast<const uint32*>(&HsB[(size_t)ib[u] * 128 + c0]);
#pragma unroll
      for (int u = 0; u < 8; u++) {
        aA.x += bf_lo(va[u]); aA.y += bf_hi(va[u]);
        aB.x += bf_lo(vb[u]); aB.y += bf_hi(vb[u]);
      }
      jA += 8; jB += 8;
    }
    while (jA + 8 <= dA) {
      int ia[8];
#pragma unroll
      for (int u = 0; u < 8; u++) ia[u] = csr_src[sA + jA + u];
      uint32 va[8];
#pragma unroll
      for (int u = 0; u < 8; u++)
        va[u] = *reinterpret_cast<const uint32*>(&HsB[(size_t)ia[u] * 128 + c0]);
#pragma unroll
      for (int u = 0; u < 8; u++) { aA.x += bf_lo(va[u]); aA.y += bf_hi(va[u]); }
      jA += 8;
    }
    while (jB + 8 <= dB) {
      int ib[8];
#pragma unroll
      for (int u = 0; u < 8; u++) ib[u] = csr_src[sB + jB + u];
      uint32 vb[8];
#pragma unroll
      for (int u = 0; u < 8; u++)
        vb[u] = *reinterpret_cast<const uint32*>(&HsB[(size_t)ib[u] * 128 + c0]);
#pragma unroll
      for (int u = 0; u < 8; u++) { aB.x += bf_lo(vb[u]); aB.y += bf_hi(vb[u]); }
      jB += 8;
    }
    if (jA + 4 <= dA && jB + 4 <= dB) {
      int ia[4], ib[4];
#pragma unroll
      for (int u = 0; u < 4; u++) ia[u] = csr_src[sA + jA + u];
#pragma unroll
      for (int u = 0; u < 4; u++) ib[u] = csr_src[sB + jB + u];
      uint32 va[4], vb[4];
#pragma unroll
      for (int u = 0; u < 4; u++)
        va[u] = *reinterpret_cast<const uint32*>(&HsB[(size_t)ia[u] * 128 + c0]);
#pragma unroll
      for (int u = 0; u < 4; u++)
        vb[u] = *reinterpret_cast<const uint32*>(&HsB[(size_t)ib[u] * 128 + c0]);
#pragma unroll
      for (int u = 0; u < 4; u++) {
        aA.x += bf_lo(va[u]); aA.y += bf_hi(va[u]);
        aB.x += bf_lo(vb[u]); aB.y += bf_hi(vb[u]);
      }
      jA += 4; jB += 4;
    }
    if (jA + 4 <= dA) {
      int ia[4];
#pragma unroll
      for (int u = 0; u < 4; u++) ia[u] = csr_src[sA + jA + u];
      uint32 va[4];
#pragma unroll
      for (int u = 0; u < 4; u++)
        va[u] = *reinterpret_cast<const uint32*>(&HsB[(size_t)ia[u] * 128 + c0]);
#pragma unroll
      for (int u = 0; u < 4; u++) { aA.x += bf_lo(va[u]); aA.y += bf_hi(va[u]); }
      jA += 4;
    }
    if (jB + 4 <= dB) {
      int ib[4];
#pragma unroll
      for (int u = 0; u < 4; u++) ib[u] = csr_src[sB + jB + u];
      uint32 vb[4];
#pragma unroll
      for (int u = 0; u < 4; u++)
        vb[u] = *reinterpret_cast<const uint32*>(&HsB[(size_t)ib[u] * 128 + c0]);
#pragma unroll
      for (int u = 0; u < 4; u++) { aB.x += bf_lo(vb[u]); aB.y += bf_hi(vb[u]); }
      jB += 4;
    }
    for (; jA < dA && jB < dB; jA++, jB++) {
      int s0 = csr_src[sA + jA], s1 = csr_src[sB + jB];
      uint32 v0 = *reinterpret_cast<const uint32*>(&HsB[(size_t)s0 * 128 + c0]);
      uint32 v1 = *reinterpret_cast<const uint32*>(&HsB[(size_t)s1 * 128 + c0]);
      aA.x += bf_lo(v0); aA.y += bf_hi(v0);
      aB.x += bf_lo(v1); aB.y += bf_hi(v1);
    }
    for (; jA < dA; jA++) {
      int s0 = csr_src[sA + jA];
      uint32 v0 = *reinterpret_cast<const uint32*>(&HsB[(size_t)s0 * 128 + c0]);
      aA.x += bf_lo(v0); aA.y += bf_hi(v0);
    }
    for (; jB < dB; jB++) {
      int s1 = csr_src[sB + jB];
      uint32 v1 = *reinterpret_cast<const uint32*>(&HsB[(size_t)s1 * 128 + c0]);
      aB.x += bf_lo(v1); aB.y += bf_hi(v1);
    }
    {
      float ri = r[iA];
      float v0 = fmaf(ri, aA.x, b.x), v1 = fmaf(ri, aA.y, b.y);
      v0 = fmaxf(v0, 0.f); v1 = fmaxf(v1, 0.f);
      y_to_hs2(v0, v1, ri, iA, wave, lane, c0, w2l, yrow, outB);
    }
    if (hasB) {
      float ri = r[iB];
      float v0 = fmaf(ri, aB.x, b.x), v1 = fmaf(ri, aB.y, b.y);
      v0 = fmaxf(v0, 0.f); v1 = fmaxf(v1, 0.f);
      y_to_hs2(v0, v1, ri, iB, wave, lane, c0, w2l, yrow, outB);
    }
  }
}

// layer-2 aggregation + column-sum (round-8 structure, COLSUM path)
__global__ __launch_bounds__(TPB) void k_aggS(
    const unsigned short* __restrict__ HsB, const float* __restrict__ r,
    const int* __restrict__ row_start, const int* __restrict__ deg,
    const int* __restrict__ csr_src, const float* __restrict__ bias,
    float* __restrict__ colsum, int N) {
  __shared__ float red[4][128];
  int wave = threadIdx.x >> 6, lane = threadIdx.x & 63;
  int gw = blockIdx.x * 4 + wave, nw = gridDim.x * 4;
  const int c0 = lane * 2;
  float2 b = *reinterpret_cast<const float2*>(&bias[c0]);
  float2 csum = make_float2(0.f, 0.f);

  for (int i0 = gw; i0 < N; i0 += 2 * nw) {
    const int iA = i0;
    const int iB = i0 + nw;
    const int hasB = (iB < N);
    int sA = __builtin_amdgcn_readfirstlane(row_start[iA]);
    int dA = __builtin_amdgcn_readfirstlane(deg[iA]);
    int sB = 0, dB = 0;
    if (hasB) {
      sB = __builtin_amdgcn_readfirstlane(row_start[iB]);
      dB = __builtin_amdgcn_readfirstlane(deg[iB]);
    }
    uint32 selfA = *reinterpret_cast<const uint32*>(&HsB[(size_t)iA * 128 + c0]);
    float2 aA = make_float2(bf_lo(selfA), bf_hi(selfA));
    float2 aB = make_float2(0.f, 0.f);
    if (hasB) {
      uint32 selfB = *reinterpret_cast<const uint32*>(&HsB[(size_t)iB * 128 + c0]);
      aB = make_float2(bf_lo(selfB), bf_hi(selfB));
    }
    int jA = 0, jB = 0;
    while (jA + 8 <= dA && jB + 8 <= dB) {
      int ia[8], ib[8];
#pragma unroll
      for (int u = 0; u < 8; u++) ia[u] = csr_src[sA + jA + u];
#pragma unroll
      for (int u = 0; u < 8; u++) ib[u] = csr_src[sB + jB + u];
      uint32 va[8], vb[8];
#pragma unroll
      for (int u = 0; u < 8; u++)
        va[u] = *reinterpret_cast<const uint32*>(&HsB[(size_t)ia[u] * 128 + c0]);
#pragma unroll
      for (int u = 0; u < 8; u++)
        vb[u] = *reinterpret_cast<const uint32*>(&HsB[(size_t)ib[u] * 128 + c0]);
#pragma unroll
      for (int u = 0; u < 8; u++) {
        aA.x += bf_lo(va[u]); aA.y += bf_hi(va[u]);
        aB.x += bf_lo(vb[u]); aB.y += bf_hi(vb[u]);
      }
      jA += 8; jB += 8;
    }
    while (jA + 8 <= dA) {
      int ia[8];
#pragma unroll
      for (int u = 0; u < 8; u++) ia[u] = csr_src[sA + jA + u];
      uint32 va[8];
#pragma unroll
      for (int u = 0; u < 8; u++)
        va[u] = *reinterpret_cast<const uint32*>(&HsB[(size_t)ia[u] * 128 + c0]);
#pragma unroll
      for (int u = 0; u < 8; u++) { aA.x += bf_lo(va[u]); aA.y += bf_hi(va[u]); }
      jA += 8;
    }
    while (jB + 8 <= dB) {
      int ib[8];
#pragma unroll
      for (int u = 0; u < 8; u++) ib[u] = csr_src[sB + jB + u];
      uint32 vb[8];
#pragma unroll
      for (int u = 0; u < 8; u++)
        vb[u] = *reinterpret_cast<const uint32*>(&HsB[(size_t)ib[u] * 128 + c0]);
#pragma unroll
      for (int u = 0; u < 8; u++) { aB.x += bf_lo(vb[u]); aB.y += bf_hi(vb[u]); }
      jB += 8;
    }
    if (jA + 4 <= dA && jB + 4 <= dB) {
      int ia[4], ib[4];
#pragma unroll
      for (int u = 0; u < 4; u++) ia[u] = csr_src[sA + jA + u];
#pragma unroll
      for (int u = 0; u < 4; u++) ib[u] = csr_src[sB + jB + u];
      uint32 va[4], vb[4];
#pragma unroll
      for (int u = 0; u < 4; u++)
        va[u] = *reinterpret_cast<const uint32*>(&HsB[(size_t)ia[u] * 128 + c0]);
#pragma unroll
      for (int u = 0; u < 4; u++)
        vb[u] = *reinterpret_cast<const uint32*>(&HsB[(size_t)ib[u] * 128 + c0]);
#pragma unroll
      for (int u = 0; u < 4; u++) {
        aA.x += bf_lo(va[u]); aA.y += bf_hi(va[u]);
        aB.x += bf_lo(vb[u]); aB.y += bf_hi(vb[u]);
      }
      jA += 4; jB += 4;
    }
    if (jA + 4 <= dA) {
      int ia[4];
#pragma unroll
      for (int u = 0; u < 4; u++) ia[u] = csr_src[sA + jA + u];
      uint32 va[4];
#pragma unroll
      for (int u = 0; u < 4; u++)
        va[u] = *reinterpret_cast<const uint32*>(&HsB[(size_t)ia[u] * 128 + c0]);
#pragma unroll
      for (int u = 0; u < 4; u++) { aA.x += bf_lo(va[u]); aA.y += bf_hi(va[u]); }
      jA += 4;
    }
    if (jB + 4 <= dB) {
      int ib[4];
#pragma unroll
      for (int u = 0; u < 4; u++) ib[u] = csr_src[sB + jB + u];
      uint32 vb[4];
#pragma unroll
      for (int u = 0; u < 4; u++)
        vb[u] = *reinterpret_cast<const uint32*>(&HsB[(size_t)ib[u] * 128 + c0]);
#pragma unroll
      for (int u = 0; u < 4; u++) { aB.x += bf_lo(vb[u]); aB.y += bf_hi(vb[u]); }
      jB += 4;
    }
    for (; jA < dA && jB < dB; jA++, jB++) {
      int s0 = csr_src[sA + jA], s1 = csr_src[sB + jB];
      uint32 v0 = *reinterpret_cast<const uint32*>(&HsB[(size_t)s0 * 128 + c0]);
      uint32 v1 = *reinterpret_cast<const uint32*>(&HsB[(size_t)s1 * 128 + c0]);
      aA.x += bf_lo(v0); aA.y += bf_hi(v0);
      aB.x += bf_lo(v1); aB.y += bf_hi(v1);
    }
    for (; jA < dA; jA++) {
      int s0 = csr_src[sA + jA];
      uint32 v0 = *reinterpret_cast<const uint32*>(&HsB[(size_t)s0 * 128 + c0]);
      aA.x += bf_lo(v0); aA.y += bf_hi(v0);
    }
    for (; jB < dB; jB++) {
      int s1 = csr_src[sB + jB];
      uint32 v1 = *reinterpret_cast<const uint32*>(&HsB[(size_t)s1 * 128 + c0]);
      aB.x += bf_lo(v1); aB.y += bf_hi(v1);
    }
    {
      float ri = r[iA];
      csum.x += fmaf(ri, aA.x, b.x);
      csum.y += fmaf(ri, aA.y, b.y);
    }
    if (hasB) {
      float ri = r[iB];
      csum.x += fmaf(ri, aB.x, b.x);
      csum.y += fmaf(ri, aB.y, b.y);
    }
  }
  red[wave][c0] = csum.x;
  red[wave][c0 + 1] = csum.y;
  __syncthreads();
  if (wave == 0) {
    float sx = red[0][c0] + red[1][c0] + red[2][c0] + red[3][c0];
    float sy = red[0][c0 + 1] + red[1][c0 + 1] + red[2][c0 + 1] + red[3][c0 + 1];
    atomicAdd(&colsum[c0], sx);
    atomicAdd(&colsum[c0 + 1], sy);
  }
}

__global__ void k_final(const float* __restrict__ colsum, float* __restrict__ out,
                        float invN) {
  int c = threadIdx.x;
  out[c] = colsum[c] * invN;
}

extern "C" void kernel_launch(void* const* d_in, const int* in_sizes, int n_in,
                              void* d_out, int out_size, void* d_ws, size_t ws_size,
                              hipStream_t stream) {
  const float* x = (const float*)d_in[0];
  const int* ep = (const int*)d_in[1];
  const float* W1 = (const float*)d_in[2];
  const float* b1 = (const float*)d_in[3];
  const float* W2 = (const float*)d_in[4];
  const float* b2 = (const float*)d_in[5];
  float* outp = (float*)d_out;

  const int N = in_sizes[0] / 128;      // 100000
  const long long E = in_sizes[1] / 2;  // 1600000

  char* ws = (char*)d_ws;
  size_t off = 0;
  auto carve = [&](size_t bytes) -> void* {
    void* p = ws + off;
    off = (off + bytes + 255) & ~(size_t)255;
    return p;
  };
  unsigned short* HsB = (unsigned short*)carve((size_t)N * 128 * 2);   // 25.6 MB
  unsigned short* Hs2B = (unsigned short*)carve((size_t)N * 128 * 2);  // 25.6 MB
  float* rr = (float*)carve((size_t)N * 4);
  int* deg = (int*)carve((size_t)N * 4);
  int* rs = (int*)carve((size_t)N * 4);
  int* cur = (int*)carve((size_t)N * 4);
  int* csr = (int*)carve((size_t)E * 4);                               // 6.4 MB
  int* bsums = (int*)carve(4096 * 4);
  int* flag = (int*)carve(256);
  float* colsum = (float*)carve(512);

  hipMemsetAsync(flag, 0, 4, stream);
  hipMemsetAsync(deg, 0, (size_t)N * 4, stream);
  hipMemsetAsync(colsum, 0, 512, stream);

  k_detect<<<1, TPB, 0, stream>>>(ep, E, flag);
  k_count<<<2048, TPB, 0, stream>>>(ep, E, flag, deg);
  int nb = (N + TPB - 1) / TPB;  // 391
  k_bsum<<<nb, TPB, 0, stream>>>(deg, N, bsums);
  k_bscan<<<1, 512, 0, stream>>>(bsums, nb);
  k_scan3<<<nb, TPB, 0, stream>>>(deg, bsums, N, rs, cur, rr);
  k_fill<<<2048, TPB, 0, stream>>>(ep, E, flag, cur, csr);

  int gblocks = (N + 31) / 32;
  // layer 1 gemm: HsB = bf16((x@W1)*r)
  k_gemm<<<gblocks, TPB, 0, stream>>>(x, W1, rr, HsB, N);
  // fused: layer-1 aggregation + relu + layer-2 gemm -> Hs2B
  k_aggF<<<2048, TPB, 0, stream>>>(HsB, rr, rs, deg, csr, b1, W2, Hs2B, N);
  // layer-2 aggregation + column sums
  k_aggS<<<2048, TPB, 0, stream>>>(Hs2B, rr, rs, deg, csr, b2, colsum, N);
  k_final<<<1, 128, 0, stream>>>(colsum, outp, 1.0f / (float)N);
}

// Round 13
// 618.014 us; speedup vs baseline: 1.6142x; 1.6142x over previous
//
#include <hip/hip_runtime.h>

#define TPB 256

typedef unsigned int uint32;
typedef float float4v __attribute__((ext_vector_type(4)));

static __device__ __forceinline__ unsigned short f2bf(float f) {
  unsigned int u = __float_as_uint(f);
  unsigned int r = (u + 0x7FFFu + ((u >> 16) & 1u)) >> 16;
  return (unsigned short)r;
}
static __device__ __forceinline__ float bf_lo(uint32 v) {
  return __uint_as_float(v << 16);
}
static __device__ __forceinline__ float bf_hi(uint32 v) {
  return __uint_as_float(v & 0xFFFF0000u);
}

// int64 staged => odd int32 words (high words) of src row are 0.
static __device__ __forceinline__ int edge_val(const int* __restrict__ ep,
                                               long long idx, int is64) {
  return is64 ? ep[2 * idx] : ep[idx];
}

__global__ void k_detect(const int* __restrict__ ep, long long E,
                         int* __restrict__ flag) {
  int lim = (E < 16384) ? (int)E : 16384;
  int found = 0;
  for (int i = threadIdx.x; i < lim; i += TPB) found |= (ep[2 * i + 1] != 0);
  if (found) atomicOr(flag, 1);
}

__global__ void k_count(const int* __restrict__ ep, long long E,
                        const int* __restrict__ flag, int* __restrict__ deg) {
  int is64 = (*flag == 0);
  long long stride = (long long)gridDim.x * blockDim.x;
  for (long long e = blockIdx.x * (long long)blockDim.x + threadIdx.x; e < E;
       e += stride) {
    int d = edge_val(ep, E + e, is64);
    atomicAdd(&deg[d], 1);
  }
}

__global__ void k_bsum(const int* __restrict__ deg, int N,
                       int* __restrict__ bsums) {
  __shared__ int lds[TPB];
  int t = threadIdx.x;
  int i = blockIdx.x * TPB + t;
  lds[t] = (i < N) ? deg[i] : 0;
  __syncthreads();
  for (int off = TPB / 2; off > 0; off >>= 1) {
    if (t < off) lds[t] += lds[t + off];
    __syncthreads();
  }
  if (t == 0) bsums[blockIdx.x] = lds[0];
}

__global__ void k_bscan(int* __restrict__ bsums, int nb) {
  __shared__ int lds[512];
  int t = threadIdx.x;
  int v = (t < nb) ? bsums[t] : 0;
  lds[t] = v;
  __syncthreads();
  for (int off = 1; off < 512; off <<= 1) {
    int x = (t >= off) ? lds[t - off] : 0;
    __syncthreads();
    lds[t] += x;
    __syncthreads();
  }
  if (t < nb) bsums[t] = lds[t] - v;  // exclusive
}

__global__ void k_scan3(const int* __restrict__ deg, const int* __restrict__ bsums,
                        int N, int* __restrict__ row_start, int* __restrict__ cursor,
                        float* __restrict__ r) {
  __shared__ int lds[TPB];
  int t = threadIdx.x;
  int i = blockIdx.x * TPB + t;
  int v = (i < N) ? deg[i] : 0;
  lds[t] = v;
  __syncthreads();
  for (int off = 1; off < TPB; off <<= 1) {
    int x = (t >= off) ? lds[t - off] : 0;
    __syncthreads();
    lds[t] += x;
    __syncthreads();
  }
  if (i < N) {
    int ex = lds[t] - v + bsums[blockIdx.x];
    row_start[i] = ex;
    cursor[i] = ex;
    r[i] = rsqrtf((float)(v + 1));
  }
}

// CSR fill + out-edge weight accumulation: w[s] += r[d] per edge (s,d)
__global__ void k_fillW(const int* __restrict__ ep, long long E,
                        const int* __restrict__ flag, int* __restrict__ cursor,
                        const float* __restrict__ rr, int* __restrict__ csr_src,
                        float* __restrict__ w) {
  int is64 = (*flag == 0);
  long long stride = (long long)gridDim.x * blockDim.x;
  for (long long e = blockIdx.x * (long long)blockDim.x + threadIdx.x; e < E;
       e += stride) {
    int s = edge_val(ep, e, is64);
    int d = edge_val(ep, E + e, is64);
    int pos = atomicAdd(&cursor[d], 1);
    __builtin_nontemporal_store(s, &csr_src[pos]);
    atomicAdd(&w[s], rr[d]);
  }
}

// out[row,:] = bf16( (X@W) * r[row] ).  W packed bf16-pairs in LDS (32 KB).
__global__ __launch_bounds__(TPB, 4) void k_gemm(
    const float* __restrict__ X, const float* __restrict__ W,
    const float* __restrict__ r, unsigned short* __restrict__ outB, int N) {
  __shared__ uint32 wl[128 * 64];  // [k][pair]
  for (int i = threadIdx.x; i < 128 * 64; i += TPB) {
    int k = i >> 6, p = i & 63;
    float2 wv = *reinterpret_cast<const float2*>(&W[k * 128 + p * 2]);
    wl[i] = (uint32)f2bf(wv.x) | ((uint32)f2bf(wv.y) << 16);
  }
  __syncthreads();
  int wave = threadIdx.x >> 6, lane = threadIdx.x & 63;
  int row0 = (blockIdx.x * 4 + wave) * 8;
  if (row0 >= N) return;
  const int c0 = lane * 2;
  float2 acc[8];
#pragma unroll
  for (int q = 0; q < 8; q++) acc[q] = make_float2(0.f, 0.f);
  for (int kk = 0; kk < 128; kk += 4) {
    float4v xv[8];
#pragma unroll
    for (int q = 0; q < 8; q++) {
      int rr = row0 + q;
      if (rr >= N) rr = N - 1;
      xv[q] = __builtin_nontemporal_load(
          reinterpret_cast<const float4v*>(&X[(size_t)rr * 128 + kk]));
    }
#pragma unroll
    for (int u = 0; u < 4; u++) {
      uint32 wv = wl[(kk + u) * 64 + lane];
      float wx = bf_lo(wv), wy = bf_hi(wv);
#pragma unroll
      for (int q = 0; q < 8; q++) {
        float xk = xv[q][u];
        acc[q].x = fmaf(xk, wx, acc[q].x);
        acc[q].y = fmaf(xk, wy, acc[q].y);
      }
    }
  }
#pragma unroll
  for (int q = 0; q < 8; q++) {
    int rr = row0 + q;
    if (rr < N) {
      float sc = r[rr];
      uint32 o = (uint32)f2bf(acc[q].x * sc) | ((uint32)f2bf(acc[q].y * sc) << 16);
      *reinterpret_cast<uint32*>(&outB[(size_t)rr * 128 + c0]) = o;
    }
  }
}

// ---------------------------------------------------------------------------
// Layer-1 gather + relu + weighted column-sum (replaces agg1+gemm2+agg2):
//   Y_i = relu( r_i*(Hs_i + sum_{src->i} Hs_src) + b1 )
//   z  += r_i*(r_i + w_i) * Y_i          (z: 128-wide colsum accumulator)
// Gather loop identical to the measured-151us round-6/8 structure.
// ---------------------------------------------------------------------------
__global__ __launch_bounds__(TPB) void k_aggZ(
    const unsigned short* __restrict__ HsB, const float* __restrict__ rr,
    const int* __restrict__ row_start, const int* __restrict__ deg,
    const int* __restrict__ csr_src, const float* __restrict__ bias,
    const float* __restrict__ w, float* __restrict__ colsum, int N) {
  __shared__ float red[4][128];
  int wave = threadIdx.x >> 6, lane = threadIdx.x & 63;
  int gw = blockIdx.x * 4 + wave, nw = gridDim.x * 4;
  const int c0 = lane * 2;
  float2 b = *reinterpret_cast<const float2*>(&bias[c0]);
  float2 csum = make_float2(0.f, 0.f);

  for (int i = gw; i < N; i += nw) {
    int start = __builtin_amdgcn_readfirstlane(row_start[i]);
    int d = __builtin_amdgcn_readfirstlane(deg[i]);
    uint32 self = *reinterpret_cast<const uint32*>(&HsB[(size_t)i * 128 + c0]);
    float2 acc = make_float2(bf_lo(self), bf_hi(self));
    int j = 0;
    for (; j + 8 <= d; j += 8) {
      int ia[8];
#pragma unroll
      for (int u = 0; u < 8; u++) ia[u] = csr_src[start + j + u];
      uint32 va[8];
#pragma unroll
      for (int u = 0; u < 8; u++)
        va[u] = *reinterpret_cast<const uint32*>(&HsB[(size_t)ia[u] * 128 + c0]);
#pragma unroll
      for (int u = 0; u < 8; u++) {
        acc.x += bf_lo(va[u]);
        acc.y += bf_hi(va[u]);
      }
    }
    if (j + 4 <= d) {
      int ia[4];
#pragma unroll
      for (int u = 0; u < 4; u++) ia[u] = csr_src[start + j + u];
      uint32 va[4];
#pragma unroll
      for (int u = 0; u < 4; u++)
        va[u] = *reinterpret_cast<const uint32*>(&HsB[(size_t)ia[u] * 128 + c0]);
#pragma unroll
      for (int u = 0; u < 4; u++) {
        acc.x += bf_lo(va[u]);
        acc.y += bf_hi(va[u]);
      }
      j += 4;
    }
    for (; j < d; j++) {
      int s = csr_src[start + j];
      uint32 v = *reinterpret_cast<const uint32*>(&HsB[(size_t)s * 128 + c0]);
      acc.x += bf_lo(v);
      acc.y += bf_hi(v);
    }
    float ri = rr[i];
    float wi = w[i];
    float v0 = fmaf(ri, acc.x, b.x), v1 = fmaf(ri, acc.y, b.y);
    v0 = fmaxf(v0, 0.f);
    v1 = fmaxf(v1, 0.f);
    float ci = ri * (ri + wi);
    csum.x = fmaf(ci, v0, csum.x);
    csum.y = fmaf(ci, v1, csum.y);
  }
  red[wave][c0] = csum.x;
  red[wave][c0 + 1] = csum.y;
  __syncthreads();
  if (wave == 0) {
    float sx = red[0][c0] + red[1][c0] + red[2][c0] + red[3][c0];
    float sy = red[0][c0 + 1] + red[1][c0 + 1] + red[2][c0 + 1] + red[3][c0 + 1];
    atomicAdd(&colsum[c0], sx);
    atomicAdd(&colsum[c0 + 1], sy);
  }
}

// out[c] = (z @ W2)[c] / N + b2[c]
__global__ void k_vm(const float* __restrict__ z, const float* __restrict__ W2,
                     const float* __restrict__ b2, float* __restrict__ out,
                     float invN) {
  int c = threadIdx.x;
  float acc = 0.f;
#pragma unroll 8
  for (int k = 0; k < 128; k++) acc = fmaf(z[k], W2[k * 128 + c], acc);
  out[c] = acc * invN + b2[c];
}

extern "C" void kernel_launch(void* const* d_in, const int* in_sizes, int n_in,
                              void* d_out, int out_size, void* d_ws, size_t ws_size,
                              hipStream_t stream) {
  const float* x = (const float*)d_in[0];
  const int* ep = (const int*)d_in[1];
  const float* W1 = (const float*)d_in[2];
  const float* b1 = (const float*)d_in[3];
  const float* W2 = (const float*)d_in[4];
  const float* b2 = (const float*)d_in[5];
  float* outp = (float*)d_out;

  const int N = in_sizes[0] / 128;      // 100000
  const long long E = in_sizes[1] / 2;  // 1600000

  char* ws = (char*)d_ws;
  size_t off = 0;
  auto carve = [&](size_t bytes) -> void* {
    void* p = ws + off;
    off = (off + bytes + 255) & ~(size_t)255;
    return p;
  };
  unsigned short* HsB = (unsigned short*)carve((size_t)N * 128 * 2);  // 25.6 MB
  float* rr = (float*)carve((size_t)N * 4);
  float* w = (float*)carve((size_t)N * 4);
  int* deg = (int*)carve((size_t)N * 4);
  int* rs = (int*)carve((size_t)N * 4);
  int* cur = (int*)carve((size_t)N * 4);
  int* csr = (int*)carve((size_t)E * 4);                              // 6.4 MB
  int* bsums = (int*)carve(4096 * 4);
  int* flag = (int*)carve(256);
  float* colsum = (float*)carve(512);

  hipMemsetAsync(flag, 0, 4, stream);
  hipMemsetAsync(deg, 0, (size_t)N * 4, stream);
  hipMemsetAsync(w, 0, (size_t)N * 4, stream);
  hipMemsetAsync(colsum, 0, 512, stream);

  k_detect<<<1, TPB, 0, stream>>>(ep, E, flag);
  k_count<<<2048, TPB, 0, stream>>>(ep, E, flag, deg);
  int nb = (N + TPB - 1) / TPB;  // 391
  k_bsum<<<nb, TPB, 0, stream>>>(deg, N, bsums);
  k_bscan<<<1, 512, 0, stream>>>(bsums, nb);
  k_scan3<<<nb, TPB, 0, stream>>>(deg, bsums, N, rs, cur, rr);
  k_fillW<<<2048, TPB, 0, stream>>>(ep, E, flag, cur, rr, csr, w);

  int gblocks = (N + 31) / 32;
  // layer 1 gemm: HsB = bf16((x@W1)*r)
  k_gemm<<<gblocks, TPB, 0, stream>>>(x, W1, rr, HsB, N);
  // gather + relu + weighted colsum  ->  z (colsum)
  k_aggZ<<<2048, TPB, 0, stream>>>(HsB, rr, rs, deg, csr, b1, w, colsum, N);
  // out = z@W2/N + b2
  k_vm<<<1, 128, 0, stream>>>(colsum, W2, b2, outp, 1.0f / (float)N);
}